// Round 7
// baseline (200.601 us; speedup 1.0000x reference)
//
#include <hip/hip_runtime.h>
#include <hip/hip_bf16.h>

#define FDIM 64
#define N_PIXELS 65536
#define N_ENTRIES 4194304
#define WAVES_PER_BLOCK 4
#define N_WAVES 8192
#define EPW 512   // entries per wave (exact: 8192*512 = 4194304)
#define PAD 64    // zero-scale pad entries after the 512

typedef unsigned int u32;
typedef u32 u32x4 __attribute__((ext_vector_type(4)));

// ---------- kernel A: tok_bf[g,:] = bf16( tokens[g,:] * exp(gamma[g]) ) ----------
__device__ __forceinline__ unsigned short f32_to_bf16_rne(float f) {
    unsigned int u = __float_as_uint(f);
    u = (u + 0x7FFFu + ((u >> 16) & 1u)) >> 16;
    return (unsigned short)u;
}

__global__ __launch_bounds__(256) void convert_tokens(
    const float4* __restrict__ tokens4,   // 480000 float4
    const float* __restrict__ gamma,
    ushort4* __restrict__ tok_bf)         // 480000 ushort4 (bf16)
{
    const int i = blockIdx.x * blockDim.x + threadIdx.x;   // exactly 480000
    const int g = i >> 4;                                   // gene row
    const float eg = __expf(gamma[g]);
    const float4 t = tokens4[i];
    ushort4 o;
    o.x = f32_to_bf16_rne(t.x * eg);
    o.y = f32_to_bf16_rne(t.y * eg);
    o.z = f32_to_bf16_rne(t.z * eg);
    o.w = f32_to_bf16_rne(t.w * eg);
    tok_bf[i] = o;
}

// ---------- kernel B: entry-partitioned, asm-forced depth-8 gather pipeline ----------
__global__ __launch_bounds__(WAVES_PER_BLOCK * 64, 8) void sgstem_main(
    const int* __restrict__ indices,
    const float* __restrict__ cnts,
    const int* __restrict__ indptr,
    const char* __restrict__ tokp,        // bf16 table base (byte-addressed)
    float* __restrict__ out)              // (N_PIXELS, 64) f32, pre-zeroed
{
    __shared__ int2 meta[WAVES_PER_BLOCK][EPW + PAD];   // {byte_off, cnt_bits}

    const int lane = threadIdx.x & 63;
    const int wave = threadIdx.x >> 6;
    const int g    = lane >> 3;          // entry slot-within-8 (0..7)
    const int fl   = lane & 7;           // uint4 slot in token row
    const int flb  = fl * 16;            // byte offset of this lane's slice

    const int wid = __builtin_amdgcn_readfirstlane(
        blockIdx.x * WAVES_PER_BLOCK + wave);
    const int e0 = wid * EPW;
    const int e1 = e0 + EPW;

    // ---- Phase A: stage 512 entries as {row byte offset, cnt} + 64-entry pad
    #pragma unroll
    for (int c = 0; c < 8; ++c) {
        const int e = e0 + c * 64 + lane;
        const int   idx = indices[e];
        const float cnt = cnts[e];
        meta[wave][c * 64 + lane] = make_int2(idx * 128, __float_as_int(cnt));
    }
    meta[wave][EPW + lane] = make_int2(0, 0);

    // ---- binary search: p = max{ i : indptr[i] <= e0 }
    int lo = 0, hi = N_PIXELS;
    while (lo < hi) {
        const int mid = (lo + hi + 1) >> 1;
        if (indptr[mid] <= e0) lo = mid; else hi = mid - 1;
    }
    int p = lo;

    while (p < N_PIXELS) {
        const int ps = indptr[p];
        if (ps >= e1) break;
        const int pe = indptr[p + 1];
        const int s = max(ps, e0);
        const int t = min(pe, e1);

        if (t > s) {
            const int r0 = s - e0;
            const int r1 = t - e0;

            float a0 = 0.f, a1 = 0.f, a2 = 0.f, a3 = 0.f;
            float a4 = 0.f, a5 = 0.f, a6 = 0.f, a7 = 0.f;

            for (int rb = r0; rb < r1; rb += 64) {
                const int q = rb + g;
                const int2 m0 = meta[wave][q];
                const int2 m1 = meta[wave][q + 8];
                const int2 m2 = meta[wave][q + 16];
                const int2 m3 = meta[wave][q + 24];
                const int2 m4 = meta[wave][q + 32];
                const int2 m5 = meta[wave][q + 40];
                const int2 m6 = meta[wave][q + 48];
                const int2 m7 = meta[wave][q + 56];

                // masked slots redirect to row 0 (hot in L1) and scale 0
                const int o0 = ((q      < r1) ? m0.x : 0) + flb;
                const int o1 = ((q +  8 < r1) ? m1.x : 0) + flb;
                const int o2 = ((q + 16 < r1) ? m2.x : 0) + flb;
                const int o3 = ((q + 24 < r1) ? m3.x : 0) + flb;
                const int o4 = ((q + 32 < r1) ? m4.x : 0) + flb;
                const int o5 = ((q + 40 < r1) ? m5.x : 0) + flb;
                const int o6 = ((q + 48 < r1) ? m6.x : 0) + flb;
                const int o7 = ((q + 56 < r1) ? m7.x : 0) + flb;

                u32x4 t0, t1, t2, t3, t4, t5, t6, t7;
                #define GLOAD(dst, off) \
                    asm volatile("global_load_dwordx4 %0, %1, %2" \
                                 : "=v"(dst) : "v"(off), "s"(tokp) : "memory")
                GLOAD(t0, o0); GLOAD(t1, o1); GLOAD(t2, o2); GLOAD(t3, o3);
                GLOAD(t4, o4); GLOAD(t5, o5); GLOAD(t6, o6); GLOAD(t7, o7);
                #undef GLOAD

                // scales (independent of loads — computed while gathers fly)
                const float s0 = (q      < r1) ? __int_as_float(m0.y) : 0.f;
                const float s1 = (q +  8 < r1) ? __int_as_float(m1.y) : 0.f;
                const float s2 = (q + 16 < r1) ? __int_as_float(m2.y) : 0.f;
                const float s3 = (q + 24 < r1) ? __int_as_float(m3.y) : 0.f;
                const float s4 = (q + 32 < r1) ? __int_as_float(m4.y) : 0.f;
                const float s5 = (q + 40 < r1) ? __int_as_float(m5.y) : 0.f;
                const float s6 = (q + 48 < r1) ? __int_as_float(m6.y) : 0.f;
                const float s7 = (q + 56 < r1) ? __int_as_float(m7.y) : 0.f;

                asm volatile("s_waitcnt vmcnt(0)" ::: "memory");
                __builtin_amdgcn_sched_barrier(0);

                #define CONSUME(tk, sc) \
                    a0 = fmaf(__uint_as_float(tk.x << 16),         sc, a0); \
                    a1 = fmaf(__uint_as_float(tk.x & 0xFFFF0000u), sc, a1); \
                    a2 = fmaf(__uint_as_float(tk.y << 16),         sc, a2); \
                    a3 = fmaf(__uint_as_float(tk.y & 0xFFFF0000u), sc, a3); \
                    a4 = fmaf(__uint_as_float(tk.z << 16),         sc, a4); \
                    a5 = fmaf(__uint_as_float(tk.z & 0xFFFF0000u), sc, a5); \
                    a6 = fmaf(__uint_as_float(tk.w << 16),         sc, a6); \
                    a7 = fmaf(__uint_as_float(tk.w & 0xFFFF0000u), sc, a7)
                CONSUME(t0, s0); CONSUME(t1, s1); CONSUME(t2, s2); CONSUME(t3, s3);
                CONSUME(t4, s4); CONSUME(t5, s5); CONSUME(t6, s6); CONSUME(t7, s7);
                #undef CONSUME
            }

            // reduce across the 8 entry-groups (lane bits 3..5)
            #pragma unroll
            for (int mask = 8; mask <= 32; mask <<= 1) {
                a0 += __shfl_xor(a0, mask);
                a1 += __shfl_xor(a1, mask);
                a2 += __shfl_xor(a2, mask);
                a3 += __shfl_xor(a3, mask);
                a4 += __shfl_xor(a4, mask);
                a5 += __shfl_xor(a5, mask);
                a6 += __shfl_xor(a6, mask);
                a7 += __shfl_xor(a7, mask);
            }

            if (g == 0) {
                const bool interior = (ps >= e0) && (pe <= e1);
                if (interior) {
                    float4* o4 = (float4*)(out + p * FDIM);
                    o4[fl * 2]     = make_float4(a0, a1, a2, a3);
                    o4[fl * 2 + 1] = make_float4(a4, a5, a6, a7);
                } else {
                    float* o = out + p * FDIM + fl * 8;
                    atomicAdd(o + 0, a0);
                    atomicAdd(o + 1, a1);
                    atomicAdd(o + 2, a2);
                    atomicAdd(o + 3, a3);
                    atomicAdd(o + 4, a4);
                    atomicAdd(o + 5, a5);
                    atomicAdd(o + 6, a6);
                    atomicAdd(o + 7, a7);
                }
            }
        }
        ++p;
    }
}

extern "C" void kernel_launch(void* const* d_in, const int* in_sizes, int n_in,
                              void* d_out, int out_size, void* d_ws, size_t ws_size,
                              hipStream_t stream) {
    const int*    indices = (const int*)d_in[0];
    const float*  cnts    = (const float*)d_in[1];
    const int*    indptr  = (const int*)d_in[2];
    const float*  gamma   = (const float*)d_in[3];
    const float4* tokens4 = (const float4*)d_in[4];
    float*        out     = (float*)d_out;

    ushort4* tok_bf = (ushort4*)d_ws;   // 3.84 MB bf16 scaled token table

    hipMemsetAsync(d_out, 0, (size_t)N_PIXELS * FDIM * sizeof(float), stream);

    convert_tokens<<<1875, 256, 0, stream>>>(tokens4, gamma, tok_bf);

    sgstem_main<<<N_WAVES / WAVES_PER_BLOCK, WAVES_PER_BLOCK * 64, 0, stream>>>(
        indices, cnts, indptr, (const char*)tok_bf, out);
}

// Round 8
// 150.681 us; speedup vs baseline: 1.3313x; 1.3313x over previous
//
#include <hip/hip_runtime.h>
#include <hip/hip_bf16.h>

#define FDIM 64
#define N_PIXELS 65536
#define N_ENTRIES 4194304
#define WAVES_PER_BLOCK 4
#define N_WAVES 8192
#define EPW 512   // entries per wave (exact: 8192*512 = 4194304)
#define PAD 64    // zero-scale pad entries after the 512

typedef unsigned int u32;
typedef u32 u32x4 __attribute__((ext_vector_type(4)));

// ---------- kernel A: tok_bf[g,:] = bf16( tokens[g,:] * exp(gamma[g]) ) ----------
__device__ __forceinline__ unsigned short f32_to_bf16_rne(float f) {
    unsigned int u = __float_as_uint(f);
    u = (u + 0x7FFFu + ((u >> 16) & 1u)) >> 16;
    return (unsigned short)u;
}

__global__ __launch_bounds__(256) void convert_tokens(
    const float4* __restrict__ tokens4,   // 480000 float4
    const float* __restrict__ gamma,
    ushort4* __restrict__ tok_bf)         // 480000 ushort4 (bf16)
{
    const int i = blockIdx.x * blockDim.x + threadIdx.x;   // exactly 480000
    const int g = i >> 4;                                   // gene row
    const float eg = __expf(gamma[g]);
    const float4 t = tokens4[i];
    ushort4 o;
    o.x = f32_to_bf16_rne(t.x * eg);
    o.y = f32_to_bf16_rne(t.y * eg);
    o.z = f32_to_bf16_rne(t.z * eg);
    o.w = f32_to_bf16_rne(t.w * eg);
    tok_bf[i] = o;
}

// ---------- kernel B: entry-partitioned, asm depth-8 gather, 4 waves/SIMD ----------
__global__ __launch_bounds__(WAVES_PER_BLOCK * 64, 4) void sgstem_main(
    const int* __restrict__ indices,
    const float* __restrict__ cnts,
    const int* __restrict__ indptr,
    const char* __restrict__ tokp,        // bf16 table base (byte-addressed)
    float* __restrict__ out)              // (N_PIXELS, 64) f32, pre-zeroed
{
    __shared__ int2 meta[WAVES_PER_BLOCK][EPW + PAD];   // {byte_off, cnt_bits}

    const int lane = threadIdx.x & 63;
    const int wave = threadIdx.x >> 6;
    const int g    = lane >> 3;          // entry slot-within-8 (0..7)
    const int fl   = lane & 7;           // uint4 slot in token row
    const int flb  = fl * 16;            // byte offset of this lane's slice

    const int wid = __builtin_amdgcn_readfirstlane(
        blockIdx.x * WAVES_PER_BLOCK + wave);
    const int e0 = wid * EPW;
    const int e1 = e0 + EPW;

    // ---- Phase A: stage 512 entries as {row byte offset, cnt} + 64-entry pad
    #pragma unroll
    for (int c = 0; c < 8; ++c) {
        const int e = e0 + c * 64 + lane;
        const int   idx = indices[e];
        const float cnt = cnts[e];
        meta[wave][c * 64 + lane] = make_int2(idx * 128, __float_as_int(cnt));
    }
    meta[wave][EPW + lane] = make_int2(0, 0);

    // ---- binary search: p = max{ i : indptr[i] <= e0 }
    int lo = 0, hi = N_PIXELS;
    while (lo < hi) {
        const int mid = (lo + hi + 1) >> 1;
        if (indptr[mid] <= e0) lo = mid; else hi = mid - 1;
    }
    int p = lo;

    while (p < N_PIXELS) {
        const int ps = indptr[p];
        if (ps >= e1) break;
        const int pe = indptr[p + 1];
        const int s = max(ps, e0);
        const int t = min(pe, e1);

        if (t > s) {
            const int r0 = s - e0;
            const int r1 = t - e0;

            float a0 = 0.f, a1 = 0.f, a2 = 0.f, a3 = 0.f;
            float a4 = 0.f, a5 = 0.f, a6 = 0.f, a7 = 0.f;

            for (int rb = r0; rb < r1; rb += 64) {
                const int q = rb + g;
                const int2 m0 = meta[wave][q];
                const int2 m1 = meta[wave][q + 8];
                const int2 m2 = meta[wave][q + 16];
                const int2 m3 = meta[wave][q + 24];
                const int2 m4 = meta[wave][q + 32];
                const int2 m5 = meta[wave][q + 40];
                const int2 m6 = meta[wave][q + 48];
                const int2 m7 = meta[wave][q + 56];

                // masked slots redirect to row 0 (hot in L1) and scale 0
                const int o0 = ((q      < r1) ? m0.x : 0) + flb;
                const int o1 = ((q +  8 < r1) ? m1.x : 0) + flb;
                const int o2 = ((q + 16 < r1) ? m2.x : 0) + flb;
                const int o3 = ((q + 24 < r1) ? m3.x : 0) + flb;
                const int o4 = ((q + 32 < r1) ? m4.x : 0) + flb;
                const int o5 = ((q + 40 < r1) ? m5.x : 0) + flb;
                const int o6 = ((q + 48 < r1) ? m6.x : 0) + flb;
                const int o7 = ((q + 56 < r1) ? m7.x : 0) + flb;

                u32x4 t0, t1, t2, t3, t4, t5, t6, t7;
                #define GLOAD(dst, off) \
                    asm volatile("global_load_dwordx4 %0, %1, %2" \
                                 : "=v"(dst) : "v"(off), "s"(tokp) : "memory")
                GLOAD(t0, o0); GLOAD(t1, o1); GLOAD(t2, o2); GLOAD(t3, o3);
                GLOAD(t4, o4); GLOAD(t5, o5); GLOAD(t6, o6); GLOAD(t7, o7);
                #undef GLOAD

                // scales (computed while gathers fly)
                const float s0 = (q      < r1) ? __int_as_float(m0.y) : 0.f;
                const float s1 = (q +  8 < r1) ? __int_as_float(m1.y) : 0.f;
                const float s2 = (q + 16 < r1) ? __int_as_float(m2.y) : 0.f;
                const float s3 = (q + 24 < r1) ? __int_as_float(m3.y) : 0.f;
                const float s4 = (q + 32 < r1) ? __int_as_float(m4.y) : 0.f;
                const float s5 = (q + 40 < r1) ? __int_as_float(m5.y) : 0.f;
                const float s6 = (q + 48 < r1) ? __int_as_float(m6.y) : 0.f;
                const float s7 = (q + 56 < r1) ? __int_as_float(m7.y) : 0.f;

                #define CONSUME(tk, sc) \
                    a0 = fmaf(__uint_as_float(tk.x << 16),         sc, a0); \
                    a1 = fmaf(__uint_as_float(tk.x & 0xFFFF0000u), sc, a1); \
                    a2 = fmaf(__uint_as_float(tk.y << 16),         sc, a2); \
                    a3 = fmaf(__uint_as_float(tk.y & 0xFFFF0000u), sc, a3); \
                    a4 = fmaf(__uint_as_float(tk.z << 16),         sc, a4); \
                    a5 = fmaf(__uint_as_float(tk.z & 0xFFFF0000u), sc, a5); \
                    a6 = fmaf(__uint_as_float(tk.w << 16),         sc, a6); \
                    a7 = fmaf(__uint_as_float(tk.w & 0xFFFF0000u), sc, a7)

                // counted wait: consume first half while second half still flies
                asm volatile("s_waitcnt vmcnt(4)" ::: "memory");
                __builtin_amdgcn_sched_barrier(0);
                CONSUME(t0, s0); CONSUME(t1, s1); CONSUME(t2, s2); CONSUME(t3, s3);
                asm volatile("s_waitcnt vmcnt(0)" ::: "memory");
                __builtin_amdgcn_sched_barrier(0);
                CONSUME(t4, s4); CONSUME(t5, s5); CONSUME(t6, s6); CONSUME(t7, s7);
                #undef CONSUME
            }

            // reduce across the 8 entry-groups (lane bits 3..5)
            #pragma unroll
            for (int mask = 8; mask <= 32; mask <<= 1) {
                a0 += __shfl_xor(a0, mask);
                a1 += __shfl_xor(a1, mask);
                a2 += __shfl_xor(a2, mask);
                a3 += __shfl_xor(a3, mask);
                a4 += __shfl_xor(a4, mask);
                a5 += __shfl_xor(a5, mask);
                a6 += __shfl_xor(a6, mask);
                a7 += __shfl_xor(a7, mask);
            }

            if (g == 0) {
                const bool interior = (ps >= e0) && (pe <= e1);
                if (interior) {
                    float4* o4 = (float4*)(out + p * FDIM);
                    o4[fl * 2]     = make_float4(a0, a1, a2, a3);
                    o4[fl * 2 + 1] = make_float4(a4, a5, a6, a7);
                } else {
                    float* o = out + p * FDIM + fl * 8;
                    atomicAdd(o + 0, a0);
                    atomicAdd(o + 1, a1);
                    atomicAdd(o + 2, a2);
                    atomicAdd(o + 3, a3);
                    atomicAdd(o + 4, a4);
                    atomicAdd(o + 5, a5);
                    atomicAdd(o + 6, a6);
                    atomicAdd(o + 7, a7);
                }
            }
        }
        ++p;
    }
}

extern "C" void kernel_launch(void* const* d_in, const int* in_sizes, int n_in,
                              void* d_out, int out_size, void* d_ws, size_t ws_size,
                              hipStream_t stream) {
    const int*    indices = (const int*)d_in[0];
    const float*  cnts    = (const float*)d_in[1];
    const int*    indptr  = (const int*)d_in[2];
    const float*  gamma   = (const float*)d_in[3];
    const float4* tokens4 = (const float4*)d_in[4];
    float*        out     = (float*)d_out;

    ushort4* tok_bf = (ushort4*)d_ws;   // 3.84 MB bf16 scaled token table

    hipMemsetAsync(d_out, 0, (size_t)N_PIXELS * FDIM * sizeof(float), stream);

    convert_tokens<<<1875, 256, 0, stream>>>(tokens4, gamma, tok_bf);

    sgstem_main<<<N_WAVES / WAVES_PER_BLOCK, WAVES_PER_BLOCK * 64, 0, stream>>>(
        indices, cnts, indptr, (const char*)tok_bf, out);
}